// Round 8
// baseline (583.318 us; speedup 1.0000x reference)
//
#include <hip/hip_runtime.h>
#include <math.h>

#define EPS_N 1e-12f
#define MARGIN 0.3f
#define INF_BITS 0x7f800000u
#define NCLS 128     // label space (randint(0,128))
#define D 512
#define PADR 256     // padded rows after fh (kept for safety margins)

typedef __attribute__((ext_vector_type(8))) short short8;   // 8 bf16 = 4 VGPRs
typedef __attribute__((ext_vector_type(4))) float float4v;  // MFMA 16x16 accum

__device__ __forceinline__ unsigned short f2bf(float f) {   // RNE bf16
    unsigned u = __float_as_uint(f);
    u += 0x7fff + ((u >> 16) & 1);
    return (unsigned short)(u >> 16);
}
__device__ __forceinline__ void gl16(const void* g, void* l) {
    // 16B async global->LDS; global addr per-lane, LDS dest = uniform base + lane*16
    __builtin_amdgcn_global_load_lds((const __attribute__((address_space(1))) void*)g,
                                     (__attribute__((address_space(3))) void*)l, 16, 0, 0);
}

// ---------------------------------------------------------------------------
// K0: one-block bucketing, coalesced-metadata (unchanged).
// ---------------------------------------------------------------------------
__global__ __launch_bounds__(1024) void k_bucket(const int* __restrict__ lab, int Bn,
        int* __restrict__ pos, int* __restrict__ labp,
        int* __restrict__ cstart_g, int* __restrict__ ccnt_g,
        float* __restrict__ meanpos, float* __restrict__ pcinv,
        int* __restrict__ poscnt, unsigned* __restrict__ minbits) {
    __shared__ int cnt[NCLS], cs[NCLS + 1], off[NCLS], sa[NCLS], sb[NCLS];
    int tid = threadIdx.x;
    if (tid < NCLS) cnt[tid] = 0;
    __syncthreads();
    for (int i = tid; i < Bn; i += 1024) atomicAdd(&cnt[lab[i] & (NCLS - 1)], 1);
    __syncthreads();
    if (tid < NCLS) sa[tid] = cnt[tid];
    __syncthreads();
    int* src = sa; int* dst = sb;
    for (int ofs = 1; ofs < NCLS; ofs <<= 1) {          // Hillis-Steele inclusive
        if (tid < NCLS) dst[tid] = src[tid] + ((tid >= ofs) ? src[tid - ofs] : 0);
        __syncthreads();
        int* t = src; src = dst; dst = t;
    }
    if (tid < NCLS) {
        int ex = src[tid] - cnt[tid];                   // exclusive
        cs[tid] = ex;
        off[tid] = ex;
        cstart_g[tid] = ex;
        ccnt_g[tid] = cnt[tid];
    }
    if (tid == 0) cs[NCLS] = Bn;
    __syncthreads();
    // coalesced per-slot metadata: class(p) = largest l with cs[l] <= p
    for (int p = tid; p < Bn; p += 1024) {
        int lo = 0, hi = NCLS - 1;
        #pragma unroll
        for (int s = 0; s < 7; ++s) {
            int mid = (lo + hi + 1) >> 1;
            if (cs[mid] <= p) lo = mid; else hi = mid - 1;
        }
        int l = lo, m = cnt[l];
        labp[p] = l;
        poscnt[p] = m;
        pcinv[p] = 1.0f / (float)m;
        meanpos[p] = 0.f;
        minbits[p] = INF_BITS;
    }
    // pos scatter (reads coalesced; only pos[] store is scattered-by-class)
    for (int i = tid; i < Bn; i += 1024) {
        int l = lab[i] & (NCLS - 1);
        pos[i] = atomicAdd(&off[l], 1);
    }
}

// ---------------------------------------------------------------------------
// K1: normalize; one wave per row, no __syncthreads (unchanged).
// ---------------------------------------------------------------------------
__global__ __launch_bounds__(256) void k_normalize(const float* __restrict__ x,
        const int* __restrict__ pos, unsigned short* __restrict__ fh,
        float* __restrict__ sqp) {
    int w = threadIdx.x >> 6, L = threadIdx.x & 63;
    int row = blockIdx.x * 4 + w;
    const float* xr = x + (size_t)row * D + L * 8;
    float4 a = *(const float4*)xr;
    float4 b = *(const float4*)(xr + 4);
    float ss = a.x * a.x;
    ss = fmaf(a.y, a.y, ss); ss = fmaf(a.z, a.z, ss); ss = fmaf(a.w, a.w, ss);
    ss = fmaf(b.x, b.x, ss); ss = fmaf(b.y, b.y, ss);
    ss = fmaf(b.z, b.z, ss); ss = fmaf(b.w, b.w, ss);
    #pragma unroll
    for (int off = 32; off; off >>= 1) ss += __shfl_xor(ss, off, 64);
    float inv = 1.0f / fmaxf(sqrtf(ss), EPS_N);
    int prow = pos[row];
    if (L == 0) sqp[prow] = ss * inv * inv;
    ushort4 h0, h1;
    h0.x = f2bf(a.x * inv); h0.y = f2bf(a.y * inv);
    h0.z = f2bf(a.z * inv); h0.w = f2bf(a.w * inv);
    h1.x = f2bf(b.x * inv); h1.y = f2bf(b.y * inv);
    h1.z = f2bf(b.z * inv); h1.w = f2bf(b.w * inv);
    unsigned short* dst = fh + (size_t)prow * D + L * 8;
    *(ushort4*)dst = h0;
    *(ushort4*)(dst + 4) = h1;
}

// ---------------------------------------------------------------------------
// K2: per-class positive stats (unchanged from R17; passed).
// ---------------------------------------------------------------------------
__global__ __launch_bounds__(256) void k_posclass(
    const unsigned short* __restrict__ fh, const float* __restrict__ sqp,
    const int* __restrict__ cstart_g, const int* __restrict__ ccnt_g,
    float* __restrict__ meanpos)
{
    const int c = blockIdx.x;
    const int s = cstart_g[c], n = ccnt_g[c];
    if (n <= 1) return;                         // no positives; meanpos stays 0

    __shared__ unsigned short SA[128 * 128];    // row chunk   [r][K128] 32 KB
    __shared__ unsigned short SB[128 * 128];    // col chunk   [r][K128] 32 KB
    __shared__ float sqr_sh[128], sqs[128], rs[128];

    const int tid = threadIdx.x, w = tid >> 6, L = tid & 63;
    const int lm = L & 15, ls = L >> 4;

    for (int rb = 0; rb < n; rb += 128) {
        const int nr = min(128, n - rb);
        __syncthreads();
        if (tid < 128) {
            rs[tid] = 0.f;
            sqr_sh[tid] = (tid < nr) ? sqp[s + rb + tid] : 0.f;
        }
        for (int cb = 0; cb < n; cb += 128) {
            const int m = min(128, n - cb);
            const bool same = (rb == cb);
            __syncthreads();                    // prior epilogue done; sqs free
            if (tid < 128) sqs[tid] = (tid < m) ? sqp[s + cb + tid] : 0.f;

            float4v acc[8][2];
            #pragma unroll
            for (int rt = 0; rt < 8; ++rt)
                #pragma unroll
                for (int ct = 0; ct < 2; ++ct) acc[rt][ct] = (float4v){0.f, 0.f, 0.f, 0.f};

            for (int k0 = 0; k0 < D; k0 += 128) {
                __syncthreads();                // prev MFMA reads done; bufs free
                #pragma unroll
                for (int q = 0; q < 8; ++q) {
                    int slot = tid + 256 * q;   // (row r = slot>>4, seg e = slot&15)
                    int r = slot >> 4;
                    int u = (slot & 15) ^ (r & 15);   // pre-swizzled global seg
                    if (r < nr)
                        gl16(fh + (size_t)(s + rb + r) * D + k0 + u * 8,
                             &SA[(w * 64 + 256 * q) * 8]);
                }
                if (!same) {
                    #pragma unroll
                    for (int q = 0; q < 8; ++q) {
                        int slot = tid + 256 * q;
                        int r = slot >> 4;
                        int u = (slot & 15) ^ (r & 15);
                        if (r < m)
                            gl16(fh + (size_t)(s + cb + r) * D + k0 + u * 8,
                                 &SB[(w * 64 + 256 * q) * 8]);
                    }
                }
                __syncthreads();                // drains vmcnt: chunk landed
                const unsigned short* Bb = same ? SA : SB;
                #pragma unroll
                for (int h = 0; h < 4; ++h) {   // K=128 in 4 MFMA sub-steps
                    short8 bf[2];
                    #pragma unroll
                    for (int ct = 0; ct < 2; ++ct) {
                        int cr = w * 32 + ct * 16 + lm;
                        bf[ct] = *(const short8*)&Bb[cr * 128 + (((h * 4 + ls) ^ (cr & 15))) * 8];
                    }
                    #pragma unroll
                    for (int rt = 0; rt < 8; ++rt) {
                        int ar = rt * 16 + lm;
                        short8 af = *(const short8*)&SA[ar * 128 + (((h * 4 + ls) ^ (ar & 15))) * 8];
                        #pragma unroll
                        for (int ct = 0; ct < 2; ++ct)
                            acc[rt][ct] = __builtin_amdgcn_mfma_f32_16x16x32_bf16(af, bf[ct], acc[rt][ct], 0, 0, 0);
                    }
                }
            }
            // epilogue: masked dist row-sums. C/D: row = rt*16+ls*4+v, col = w*32+ct*16+lm
            #pragma unroll
            for (int rt = 0; rt < 8; ++rt) {
                #pragma unroll
                for (int v = 0; v < 4; ++v) {
                    int ri = rt * 16 + ls * 4 + v;
                    float sr = sqr_sh[ri];
                    float sum = 0.f;
                    #pragma unroll
                    for (int ct = 0; ct < 2; ++ct) {
                        int ci = w * 32 + ct * 16 + lm;
                        float d2 = sr + sqs[ci] - 2.0f * acc[rt][ct][v];
                        bool ok = (ri < nr) && (ci < m) && (rb + ri != cb + ci) && (d2 > 0.f);
                        sum += ok ? sqrtf(d2) : 0.f;
                    }
                    #pragma unroll
                    for (int off = 8; off; off >>= 1) sum += __shfl_xor(sum, off, 64);
                    if (lm == 0 && sum != 0.f) atomicAdd(&rs[ri], sum);
                }
            }
        }
        __syncthreads();
        if (tid < nr) meanpos[s + rb + tid] = rs[tid];   // single writer: plain store
    }
}

// ---------------------------------------------------------------------------
// K3 (R19): R16 geometry at R8 residency. 256x128 tile, 4 waves (2Mx2N),
// wave = 128x64, acc 8x4 -> 12 ds_read : 32 MFMA per wave-K32 (ceiling 26.5%
// vs R8's 20.2%), but with BK=32 single-buffer LDS (24 KB + 4.6 KB metadata)
// so 4 blocks/CU co-reside — the antiphase regime where R8 achieved ~97% of
// its ceiling (R16's 2 blocks/CU only reached 60%). 2-barrier loop, 16 kts.
// Grid: 1056 triangular 256x128 blocks (R16-verified decode + dual-side
// epilogue), 1056 = 8*132 XCD-bijective swizzle.
// ---------------------------------------------------------------------------
__global__ __launch_bounds__(256, 4) void k_minsh_mfma(
    const unsigned short* __restrict__ fh, const float* __restrict__ sqp,
    const int* __restrict__ labp, const float* __restrict__ meanpos,
    const float* __restrict__ pcinv, unsigned* __restrict__ minbits)
{
    // --- XCD swizzle (1056 = 8*132, bijective) + triangular-band decode ---
    int t = (blockIdx.x & 7) * 132 + (blockIdx.x >> 3);
    // blocks before row-tile I: C(I) = I*(I+1); row I has 2I+2 col-tiles
    int I = (int)((sqrtf(4.0f * (float)t + 1.0f) - 1.0f) * 0.5f);
    while ((I + 1) * (I + 2) <= t) ++I;
    while (I * (I + 1) > t) --I;
    const int J = t - I * (I + 1);
    const int i0 = I * 256;      // 256 output rows
    const int j0 = J * 128;      // 128 output cols (j0 <= i0+128)

    __shared__ unsigned short SA[256 * 32];    // 16 KB (BK=32)
    __shared__ unsigned short SB[128 * 32];    //  8 KB
    __shared__ float s_mp2r[256], s_sqr[256], s_mp2c[128], s_sqc[128];
    __shared__ int s_labr[256], s_labc[128];

    const int tid = threadIdx.x;
    const int w = tid >> 6, L = tid & 63;
    const int lm = L & 15, ls = L >> 4;
    const int wm = w >> 1, wn = w & 1;          // 2M x 2N wave grid

    // metadata (each thread fills its own slots; loop barriers cover visibility)
    {
        int p = i0 + tid;
        float mp = meanpos[p] * pcinv[p];
        s_mp2r[tid] = mp * mp;
        s_sqr[tid]  = sqp[p];
        s_labr[tid] = labp[p];
        if (tid < 128) {
            int pq = j0 + tid;
            float mq = meanpos[pq] * pcinv[pq];
            s_mp2c[tid] = mq * mq;
            s_sqc[tid]  = sqp[pq];
            s_labc[tid] = labp[pq];
        }
    }

    // --- pre-swizzled staging sources: LDS 16B-slot s = (row r = s>>2,
    // seg e = s&3) holds global seg u = e ^ (r&3) (both-sides swizzle).
    const unsigned short* srcA[4];
    #pragma unroll
    for (int q = 0; q < 4; ++q) {
        int s = tid + 256 * q;                  // A slot 0..1023
        int r = s >> 2;
        int u = (s & 3) ^ (r & 3);
        srcA[q] = fh + (size_t)(i0 + r) * D + u * 8;
    }
    const unsigned short* srcB[2];
    #pragma unroll
    for (int q = 0; q < 2; ++q) {
        int s = tid + 256 * q;                  // B slot 0..511
        int r = s >> 2;
        int u = (s & 3) ^ (r & 3);
        srcB[q] = fh + (size_t)(j0 + r) * D + u * 8;
    }

    float4v acc[8][4];
    #pragma unroll
    for (int mi = 0; mi < 8; ++mi)
        #pragma unroll
        for (int ni = 0; ni < 4; ++ni) acc[mi][ni] = (float4v){0.f, 0.f, 0.f, 0.f};

    for (int kt = 0; kt < 16; ++kt) {
        const int ko = kt * 32;                 // ushort offset of K-chunk
        __syncthreads();                        // prev compute done; buf free
        #pragma unroll
        for (int q = 0; q < 4; ++q)
            gl16(srcA[q] + ko, &SA[(w * 64 + 256 * q) * 8]);
        #pragma unroll
        for (int q = 0; q < 2; ++q)
            gl16(srcB[q] + ko, &SB[(w * 64 + 256 * q) * 8]);
        __syncthreads();                        // drains vmcnt: chunk landed
        short8 af[8], bf[4];
        #pragma unroll
        for (int mi = 0; mi < 8; ++mi) {
            int r = wm * 128 + mi * 16 + lm;
            af[mi] = *(const short8*)&SA[r * 32 + ((ls ^ (r & 3)) << 3)];
        }
        #pragma unroll
        for (int ni = 0; ni < 4; ++ni) {
            int rb = wn * 64 + ni * 16 + lm;
            bf[ni] = *(const short8*)&SB[rb * 32 + ((ls ^ (rb & 3)) << 3)];
        }
        #pragma unroll
        for (int ni = 0; ni < 4; ++ni)
            #pragma unroll
            for (int mi = 0; mi < 8; ++mi)
                acc[mi][ni] = __builtin_amdgcn_mfma_f32_16x16x32_bf16(af[mi], bf[ni], acc[mi][ni], 0, 0, 0);
    }

    // --- d2-space dual-side epilogue (R16-verified).
    // C/D: row = wm*128 + mi*16 + ls*4 + v, col = wn*64 + ni*16 + lm
    const float INFF = __uint_as_float(INF_BITS);
    float sc[4], mp2c[4];
    int lc[4];
    #pragma unroll
    for (int ni = 0; ni < 4; ++ni) {
        int cl = wn * 64 + ni * 16 + lm;
        sc[ni]   = s_sqc[cl];
        mp2c[ni] = s_mp2c[cl];
        lc[ni]   = s_labc[cl];
    }
    float vminc[4];
    #pragma unroll
    for (int ni = 0; ni < 4; ++ni) vminc[ni] = INFF;

    #pragma unroll
    for (int mi = 0; mi < 8; ++mi) {
        #pragma unroll
        for (int v = 0; v < 4; ++v) {
            int rl = wm * 128 + mi * 16 + ls * 4 + v;
            float mp2r = s_mp2r[rl];
            float sr   = s_sqr[rl];
            int   li   = s_labr[rl];
            float vminr = INFF;
            #pragma unroll
            for (int ni = 0; ni < 4; ++ni) {
                float d2 = fmaf(-2.0f, acc[mi][ni][v], sr + sc[ni]);
                bool neq = (li != lc[ni]);
                vminr     = fminf(vminr,     (neq && d2 > mp2r)     ? d2 : INFF);
                vminc[ni] = fminf(vminc[ni], (neq && d2 > mp2c[ni]) ? d2 : INFF);
            }
            #pragma unroll
            for (int off = 8; off; off >>= 1)
                vminr = fminf(vminr, __shfl_xor(vminr, off, 64));
            if (lm == 0 && __float_as_uint(vminr) != INF_BITS)
                atomicMin(&minbits[i0 + rl], __float_as_uint(vminr));
        }
    }
    #pragma unroll
    for (int ni = 0; ni < 4; ++ni) {
        float vc = vminc[ni];
        vc = fminf(vc, __shfl_xor(vc, 16, 64));
        vc = fminf(vc, __shfl_xor(vc, 32, 64));
        if (ls == 0 && __float_as_uint(vc) != INF_BITS)
            atomicMin(&minbits[j0 + wn * 64 + ni * 16 + lm], __float_as_uint(vc));
    }
}

// ---------------------------------------------------------------------------
// K4: final reduction (unchanged).
// ---------------------------------------------------------------------------
__global__ __launch_bounds__(1024) void k_finish(const float* __restrict__ meanpos,
        const float* __restrict__ pcinv, const int* __restrict__ poscnt,
        const unsigned* __restrict__ minbits, float* __restrict__ out, int Bn) {
    float lsum = 0.f; int lcnt = 0;
    for (int i = threadIdx.x; i < Bn; i += 1024) {
        int pc = poscnt[i];
        bool valid = (pc > 1) && (pc < Bn);
        unsigned mb = minbits[i];
        if (valid && mb != INF_BITS) {
            float v = fmaf(meanpos[i], pcinv[i], MARGIN - sqrtf(__uint_as_float(mb)));
            lsum += (v > 0.f) ? v : 0.f;
            lcnt += 1;
        }
    }
    __shared__ float ssum[16]; __shared__ int scnt[16];
    int lane = threadIdx.x & 63, wid = threadIdx.x >> 6;
    #pragma unroll
    for (int off = 32; off; off >>= 1) {
        lsum += __shfl_down(lsum, off, 64);
        lcnt += __shfl_down(lcnt, off, 64);
    }
    if (lane == 0) { ssum[wid] = lsum; scnt[wid] = lcnt; }
    __syncthreads();
    if (threadIdx.x == 0) {
        float s = 0.f; int c = 0;
        #pragma unroll
        for (int q = 0; q < 16; ++q) { s += ssum[q]; c += scnt[q]; }
        out[0] = (c > 0) ? s / (float)c : 0.f;
    }
}

// ---------------------------------------------------------------------------
extern "C" void kernel_launch(void* const* d_in, const int* in_sizes, int n_in,
                              void* d_out, int out_size, void* d_ws, size_t ws_size,
                              hipStream_t stream) {
    const float* x = (const float*)d_in[0];
    const int* lab = (const int*)d_in[1];
    int Bn = in_sizes[1];                 // 8192; D fixed at 512

    size_t nd = (size_t)(Bn + PADR) * D;
    unsigned short* fh = (unsigned short*)d_ws;
    float* sqp        = (float*)(fh + nd);
    float* meanpos    = sqp + Bn;         // raw dist-sums
    float* pcinv      = meanpos + Bn;
    int* poscnt       = (int*)(pcinv + Bn);
    unsigned* minbits = (unsigned*)(poscnt + Bn);
    int* pos          = (int*)(minbits + Bn);
    int* labp         = pos + Bn;
    int* cstart_g     = labp + Bn;
    int* ccnt_g       = cstart_g + NCLS;

    k_bucket<<<1, 1024, 0, stream>>>(lab, Bn, pos, labp, cstart_g, ccnt_g,
                                     meanpos, pcinv, poscnt, minbits);
    k_normalize<<<Bn / 4, 256, 0, stream>>>(x, pos, fh, sqp);
    k_posclass<<<NCLS, 256, 0, stream>>>(fh, sqp, cstart_g, ccnt_g, meanpos);
    int nbr = Bn / 256;                   // 32 row-tiles
    int T = nbr * nbr + nbr;              // sum_I (2I+2) = 1056 = 8*132
    k_minsh_mfma<<<T, 256, 0, stream>>>(fh, sqp, labp, meanpos, pcinv, minbits);
    k_finish<<<1, 1024, 0, stream>>>(meanpos, pcinv, poscnt, minbits,
                                     (float*)d_out, Bn);
}

// Round 9
// 162.719 us; speedup vs baseline: 3.5848x; 3.5848x over previous
//
#include <hip/hip_runtime.h>
#include <math.h>

#define EPS_N 1e-12f
#define MARGIN 0.3f
#define INF_BITS 0x7f800000u
#define NCLS 128     // label space (randint(0,128))
#define D 512
#define PADR 256     // padded rows after fh (kept for safety margins)

typedef __attribute__((ext_vector_type(8))) short short8;   // 8 bf16 = 4 VGPRs
typedef __attribute__((ext_vector_type(4))) float float4v;  // MFMA 16x16 accum

__device__ __forceinline__ unsigned short f2bf(float f) {   // RNE bf16
    unsigned u = __float_as_uint(f);
    u += 0x7fff + ((u >> 16) & 1);
    return (unsigned short)(u >> 16);
}
__device__ __forceinline__ void gl16(const void* g, void* l) {
    // 16B async global->LDS; global addr per-lane, LDS dest = uniform base + lane*16
    __builtin_amdgcn_global_load_lds((const __attribute__((address_space(1))) void*)g,
                                     (__attribute__((address_space(3))) void*)l, 16, 0, 0);
}

// ---------------------------------------------------------------------------
// K0: one-block bucketing, coalesced-metadata (unchanged).
// ---------------------------------------------------------------------------
__global__ __launch_bounds__(1024) void k_bucket(const int* __restrict__ lab, int Bn,
        int* __restrict__ pos, int* __restrict__ labp,
        int* __restrict__ cstart_g, int* __restrict__ ccnt_g,
        float* __restrict__ meanpos, float* __restrict__ pcinv,
        int* __restrict__ poscnt, unsigned* __restrict__ minbits) {
    __shared__ int cnt[NCLS], cs[NCLS + 1], off[NCLS], sa[NCLS], sb[NCLS];
    int tid = threadIdx.x;
    if (tid < NCLS) cnt[tid] = 0;
    __syncthreads();
    for (int i = tid; i < Bn; i += 1024) atomicAdd(&cnt[lab[i] & (NCLS - 1)], 1);
    __syncthreads();
    if (tid < NCLS) sa[tid] = cnt[tid];
    __syncthreads();
    int* src = sa; int* dst = sb;
    for (int ofs = 1; ofs < NCLS; ofs <<= 1) {          // Hillis-Steele inclusive
        if (tid < NCLS) dst[tid] = src[tid] + ((tid >= ofs) ? src[tid - ofs] : 0);
        __syncthreads();
        int* t = src; src = dst; dst = t;
    }
    if (tid < NCLS) {
        int ex = src[tid] - cnt[tid];                   // exclusive
        cs[tid] = ex;
        off[tid] = ex;
        cstart_g[tid] = ex;
        ccnt_g[tid] = cnt[tid];
    }
    if (tid == 0) cs[NCLS] = Bn;
    __syncthreads();
    // coalesced per-slot metadata: class(p) = largest l with cs[l] <= p
    for (int p = tid; p < Bn; p += 1024) {
        int lo = 0, hi = NCLS - 1;
        #pragma unroll
        for (int s = 0; s < 7; ++s) {
            int mid = (lo + hi + 1) >> 1;
            if (cs[mid] <= p) lo = mid; else hi = mid - 1;
        }
        int l = lo, m = cnt[l];
        labp[p] = l;
        poscnt[p] = m;
        pcinv[p] = 1.0f / (float)m;
        meanpos[p] = 0.f;
        minbits[p] = INF_BITS;
    }
    // pos scatter (reads coalesced; only pos[] store is scattered-by-class)
    for (int i = tid; i < Bn; i += 1024) {
        int l = lab[i] & (NCLS - 1);
        pos[i] = atomicAdd(&off[l], 1);
    }
}

// ---------------------------------------------------------------------------
// K1: normalize; one wave per row, no __syncthreads (unchanged).
// ---------------------------------------------------------------------------
__global__ __launch_bounds__(256) void k_normalize(const float* __restrict__ x,
        const int* __restrict__ pos, unsigned short* __restrict__ fh,
        float* __restrict__ sqp) {
    int w = threadIdx.x >> 6, L = threadIdx.x & 63;
    int row = blockIdx.x * 4 + w;
    const float* xr = x + (size_t)row * D + L * 8;
    float4 a = *(const float4*)xr;
    float4 b = *(const float4*)(xr + 4);
    float ss = a.x * a.x;
    ss = fmaf(a.y, a.y, ss); ss = fmaf(a.z, a.z, ss); ss = fmaf(a.w, a.w, ss);
    ss = fmaf(b.x, b.x, ss); ss = fmaf(b.y, b.y, ss);
    ss = fmaf(b.z, b.z, ss); ss = fmaf(b.w, b.w, ss);
    #pragma unroll
    for (int off = 32; off; off >>= 1) ss += __shfl_xor(ss, off, 64);
    float inv = 1.0f / fmaxf(sqrtf(ss), EPS_N);
    int prow = pos[row];
    if (L == 0) sqp[prow] = ss * inv * inv;
    ushort4 h0, h1;
    h0.x = f2bf(a.x * inv); h0.y = f2bf(a.y * inv);
    h0.z = f2bf(a.z * inv); h0.w = f2bf(a.w * inv);
    h1.x = f2bf(b.x * inv); h1.y = f2bf(b.y * inv);
    h1.z = f2bf(b.z * inv); h1.w = f2bf(b.w * inv);
    unsigned short* dst = fh + (size_t)prow * D + L * 8;
    *(ushort4*)dst = h0;
    *(ushort4*)(dst + 4) = h1;
}

// ---------------------------------------------------------------------------
// K2: per-class positive stats (unchanged from R17; measured-good).
// ---------------------------------------------------------------------------
__global__ __launch_bounds__(256) void k_posclass(
    const unsigned short* __restrict__ fh, const float* __restrict__ sqp,
    const int* __restrict__ cstart_g, const int* __restrict__ ccnt_g,
    float* __restrict__ meanpos)
{
    const int c = blockIdx.x;
    const int s = cstart_g[c], n = ccnt_g[c];
    if (n <= 1) return;                         // no positives; meanpos stays 0

    __shared__ unsigned short SA[128 * 128];    // row chunk   [r][K128] 32 KB
    __shared__ unsigned short SB[128 * 128];    // col chunk   [r][K128] 32 KB
    __shared__ float sqr_sh[128], sqs[128], rs[128];

    const int tid = threadIdx.x, w = tid >> 6, L = tid & 63;
    const int lm = L & 15, ls = L >> 4;

    for (int rb = 0; rb < n; rb += 128) {
        const int nr = min(128, n - rb);
        __syncthreads();
        if (tid < 128) {
            rs[tid] = 0.f;
            sqr_sh[tid] = (tid < nr) ? sqp[s + rb + tid] : 0.f;
        }
        for (int cb = 0; cb < n; cb += 128) {
            const int m = min(128, n - cb);
            const bool same = (rb == cb);
            __syncthreads();                    // prior epilogue done; sqs free
            if (tid < 128) sqs[tid] = (tid < m) ? sqp[s + cb + tid] : 0.f;

            float4v acc[8][2];
            #pragma unroll
            for (int rt = 0; rt < 8; ++rt)
                #pragma unroll
                for (int ct = 0; ct < 2; ++ct) acc[rt][ct] = (float4v){0.f, 0.f, 0.f, 0.f};

            for (int k0 = 0; k0 < D; k0 += 128) {
                __syncthreads();                // prev MFMA reads done; bufs free
                #pragma unroll
                for (int q = 0; q < 8; ++q) {
                    int slot = tid + 256 * q;   // (row r = slot>>4, seg e = slot&15)
                    int r = slot >> 4;
                    int u = (slot & 15) ^ (r & 15);   // pre-swizzled global seg
                    if (r < nr)
                        gl16(fh + (size_t)(s + rb + r) * D + k0 + u * 8,
                             &SA[(w * 64 + 256 * q) * 8]);
                }
                if (!same) {
                    #pragma unroll
                    for (int q = 0; q < 8; ++q) {
                        int slot = tid + 256 * q;
                        int r = slot >> 4;
                        int u = (slot & 15) ^ (r & 15);
                        if (r < m)
                            gl16(fh + (size_t)(s + cb + r) * D + k0 + u * 8,
                                 &SB[(w * 64 + 256 * q) * 8]);
                    }
                }
                __syncthreads();                // drains vmcnt: chunk landed
                const unsigned short* Bb = same ? SA : SB;
                #pragma unroll
                for (int h = 0; h < 4; ++h) {   // K=128 in 4 MFMA sub-steps
                    short8 bf[2];
                    #pragma unroll
                    for (int ct = 0; ct < 2; ++ct) {
                        int cr = w * 32 + ct * 16 + lm;
                        bf[ct] = *(const short8*)&Bb[cr * 128 + (((h * 4 + ls) ^ (cr & 15))) * 8];
                    }
                    #pragma unroll
                    for (int rt = 0; rt < 8; ++rt) {
                        int ar = rt * 16 + lm;
                        short8 af = *(const short8*)&SA[ar * 128 + (((h * 4 + ls) ^ (ar & 15))) * 8];
                        #pragma unroll
                        for (int ct = 0; ct < 2; ++ct)
                            acc[rt][ct] = __builtin_amdgcn_mfma_f32_16x16x32_bf16(af, bf[ct], acc[rt][ct], 0, 0, 0);
                    }
                }
            }
            // epilogue: masked dist row-sums. C/D: row = rt*16+ls*4+v, col = w*32+ct*16+lm
            #pragma unroll
            for (int rt = 0; rt < 8; ++rt) {
                #pragma unroll
                for (int v = 0; v < 4; ++v) {
                    int ri = rt * 16 + ls * 4 + v;
                    float sr = sqr_sh[ri];
                    float sum = 0.f;
                    #pragma unroll
                    for (int ct = 0; ct < 2; ++ct) {
                        int ci = w * 32 + ct * 16 + lm;
                        float d2 = sr + sqs[ci] - 2.0f * acc[rt][ct][v];
                        bool ok = (ri < nr) && (ci < m) && (rb + ri != cb + ci) && (d2 > 0.f);
                        sum += ok ? sqrtf(d2) : 0.f;
                    }
                    #pragma unroll
                    for (int off = 8; off; off >>= 1) sum += __shfl_xor(sum, off, 64);
                    if (lm == 0 && sum != 0.f) atomicAdd(&rs[ri], sum);
                }
            }
        }
        __syncthreads();
        if (tid < nr) meanpos[s + rb + tid] = rs[tid];   // single writer: plain store
    }
}

// ---------------------------------------------------------------------------
// K3: VERBATIM R8 structure (measured best across R12-R19 map: 64-73 us,
// ~ceiling for its LDS traffic; all restructures lost). ONE change vs
// Round 6: XCD-bijective block swizzle (2080 = 8*260) — triangular decode
// gives consecutive t the same j0 panel, so each XCD's 260-tile chunk keeps
// that panel L2-resident (R18 measured FETCH 63 MB w/ swizzle vs 99 without).
// NOTE: acc 4x4 (64 AGPR) + ~64 VGPR = 128 unified regs — exactly the
// __launch_bounds__(256,4) cap; any bigger acc spills (R19 post-mortem).
// ---------------------------------------------------------------------------
#define BKG 64

__global__ __launch_bounds__(256, 4) void k_minsh_mfma(
    const unsigned short* __restrict__ fh, const float* __restrict__ sqp,
    const int* __restrict__ labp, const float* __restrict__ meanpos,
    const float* __restrict__ pcinv, unsigned* __restrict__ minbits)
{
    int t = (blockIdx.x & 7) * 260 + (blockIdx.x >> 3);   // XCD-bijective
    int rq = (int)((sqrtf(8.0f * (float)t + 1.0f) - 1.0f) * 0.5f);
    while ((rq + 1) * (rq + 2) / 2 <= t) ++rq;
    while (rq * (rq + 1) / 2 > t) --rq;
    int cq = t - rq * (rq + 1) / 2;
    const int i0 = cq * 128, j0 = rq * 128;
    const bool diag = (i0 == j0);

    __shared__ unsigned short LA[2][128 * BKG];   // 32 KB
    __shared__ float s_mp2r[128], s_mp2c[128], s_sqr[128], s_sqc[128];
    __shared__ int s_labr[128], s_labc[128];

    const int tid = threadIdx.x;
    const int w = tid >> 6, L = tid & 63;

    if (tid < 128) {
        float mp = meanpos[i0 + tid] * pcinv[i0 + tid];
        s_mp2r[tid] = mp * mp;
        s_sqr[tid]  = sqp[i0 + tid];
        s_labr[tid] = labp[i0 + tid];
    } else {
        int q = tid - 128;
        float mp = meanpos[j0 + q] * pcinv[j0 + q];
        s_mp2c[q] = mp * mp;
        s_sqc[q]  = sqp[j0 + q];
        s_labc[q] = labp[j0 + q];
    }

    const unsigned short* msrc = fh + (size_t)((w < 2) ? i0 : j0) * D;
    unsigned short* mylds = &LA[(w < 2) ? 0 : 1][(w & 1) * 64 * BKG];
    const int srow = L >> 3;
    const int sseg = L & 7;

    float4v acc[4][4];
    #pragma unroll
    for (int a = 0; a < 4; ++a)
        #pragma unroll
        for (int bq = 0; bq < 4; ++bq) acc[a][bq] = (float4v){0.f, 0.f, 0.f, 0.f};

    const int rw = (w >> 1) * 64, cw = (w & 1) * 64;
    const int lm = L & 15, ls = L >> 4;

    for (int k0 = 0; k0 < D; k0 += BKG) {
        __syncthreads();
        #pragma unroll
        for (int it = 0; it < 8; ++it) {
            int rmat = (w & 1) * 64 + it * 8 + srow;
            int seg = sseg ^ (rmat & 7);
            gl16(msrc + (size_t)rmat * D + k0 + seg * 8, mylds + it * 512);
        }
        __syncthreads();
        #pragma unroll
        for (int h = 0; h < 2; ++h) {
            short8 ah[4], bh[4];
            #pragma unroll
            for (int mi = 0; mi < 4; ++mi) {
                int r = rw + mi * 16 + lm;
                int slot = r * 8 + ((h * 4 + ls) ^ (r & 7));
                ah[mi] = *(const short8*)&LA[0][slot * 8];
            }
            #pragma unroll
            for (int ni = 0; ni < 4; ++ni) {
                int cc = cw + ni * 16 + lm;
                int slot = cc * 8 + ((h * 4 + ls) ^ (cc & 7));
                bh[ni] = *(const short8*)&LA[1][slot * 8];
            }
            #pragma unroll
            for (int ni = 0; ni < 4; ++ni)
                #pragma unroll
                for (int mi = 0; mi < 4; ++mi)
                    acc[mi][ni] = __builtin_amdgcn_mfma_f32_16x16x32_bf16(ah[mi], bh[ni], acc[mi][ni], 0, 0, 0);
        }
    }

    // d2-space epilogue. C/D: row = rw+mi*16+ls*4+v, col = cw+ni*16+lm
    const float INFF = __uint_as_float(INF_BITS);
    float sc[4], mp2c[4];
    int lc[4];
    #pragma unroll
    for (int ni = 0; ni < 4; ++ni) {
        int cl = cw + ni * 16 + lm;
        sc[ni]   = s_sqc[cl];
        mp2c[ni] = s_mp2c[cl];
        lc[ni]   = s_labc[cl];
    }
    float vminc[4];
    #pragma unroll
    for (int ni = 0; ni < 4; ++ni) vminc[ni] = INFF;

    #pragma unroll
    for (int mi = 0; mi < 4; ++mi) {
        #pragma unroll
        for (int v = 0; v < 4; ++v) {
            int rl = rw + mi * 16 + ls * 4 + v;
            float mp2r = s_mp2r[rl];
            float sr   = s_sqr[rl];
            int   li   = s_labr[rl];
            float vminr = INFF;
            #pragma unroll
            for (int ni = 0; ni < 4; ++ni) {
                float d2 = fmaf(-2.0f, acc[mi][ni][v], sr + sc[ni]);
                bool neq = (li != lc[ni]);
                vminr     = fminf(vminr,     (neq && d2 > mp2r)     ? d2 : INFF);
                vminc[ni] = fminf(vminc[ni], (neq && d2 > mp2c[ni]) ? d2 : INFF);
            }
            #pragma unroll
            for (int off = 8; off; off >>= 1)
                vminr = fminf(vminr, __shfl_xor(vminr, off, 64));
            if (lm == 0 && __float_as_uint(vminr) != INF_BITS)
                atomicMin(&minbits[i0 + rl], __float_as_uint(vminr));
        }
    }
    if (!diag) {
        #pragma unroll
        for (int ni = 0; ni < 4; ++ni) {
            float vc = vminc[ni];
            vc = fminf(vc, __shfl_xor(vc, 16, 64));
            vc = fminf(vc, __shfl_xor(vc, 32, 64));
            if (ls == 0 && __float_as_uint(vc) != INF_BITS)
                atomicMin(&minbits[j0 + cw + ni * 16 + lm], __float_as_uint(vc));
        }
    }
}

// ---------------------------------------------------------------------------
// K4: final reduction (unchanged).
// ---------------------------------------------------------------------------
__global__ __launch_bounds__(1024) void k_finish(const float* __restrict__ meanpos,
        const float* __restrict__ pcinv, const int* __restrict__ poscnt,
        const unsigned* __restrict__ minbits, float* __restrict__ out, int Bn) {
    float lsum = 0.f; int lcnt = 0;
    for (int i = threadIdx.x; i < Bn; i += 1024) {
        int pc = poscnt[i];
        bool valid = (pc > 1) && (pc < Bn);
        unsigned mb = minbits[i];
        if (valid && mb != INF_BITS) {
            float v = fmaf(meanpos[i], pcinv[i], MARGIN - sqrtf(__uint_as_float(mb)));
            lsum += (v > 0.f) ? v : 0.f;
            lcnt += 1;
        }
    }
    __shared__ float ssum[16]; __shared__ int scnt[16];
    int lane = threadIdx.x & 63, wid = threadIdx.x >> 6;
    #pragma unroll
    for (int off = 32; off; off >>= 1) {
        lsum += __shfl_down(lsum, off, 64);
        lcnt += __shfl_down(lcnt, off, 64);
    }
    if (lane == 0) { ssum[wid] = lsum; scnt[wid] = lcnt; }
    __syncthreads();
    if (threadIdx.x == 0) {
        float s = 0.f; int c = 0;
        #pragma unroll
        for (int q = 0; q < 16; ++q) { s += ssum[q]; c += scnt[q]; }
        out[0] = (c > 0) ? s / (float)c : 0.f;
    }
}

// ---------------------------------------------------------------------------
extern "C" void kernel_launch(void* const* d_in, const int* in_sizes, int n_in,
                              void* d_out, int out_size, void* d_ws, size_t ws_size,
                              hipStream_t stream) {
    const float* x = (const float*)d_in[0];
    const int* lab = (const int*)d_in[1];
    int Bn = in_sizes[1];                 // 8192; D fixed at 512

    size_t nd = (size_t)(Bn + PADR) * D;
    unsigned short* fh = (unsigned short*)d_ws;
    float* sqp        = (float*)(fh + nd);
    float* meanpos    = sqp + Bn;         // raw dist-sums
    float* pcinv      = meanpos + Bn;
    int* poscnt       = (int*)(pcinv + Bn);
    unsigned* minbits = (unsigned*)(poscnt + Bn);
    int* pos          = (int*)(minbits + Bn);
    int* labp         = pos + Bn;
    int* cstart_g     = labp + Bn;
    int* ccnt_g       = cstart_g + NCLS;

    k_bucket<<<1, 1024, 0, stream>>>(lab, Bn, pos, labp, cstart_g, ccnt_g,
                                     meanpos, pcinv, poscnt, minbits);
    k_normalize<<<Bn / 4, 256, 0, stream>>>(x, pos, fh, sqp);
    k_posclass<<<NCLS, 256, 0, stream>>>(fh, sqp, cstart_g, ccnt_g, meanpos);
    int nb = Bn / 128;
    int T = nb * (nb + 1) / 2;            // 2080 = 8*260 (XCD-bijective)
    k_minsh_mfma<<<T, 256, 0, stream>>>(fh, sqp, labp, meanpos, pcinv, minbits);
    k_finish<<<1, 1024, 0, stream>>>(meanpos, pcinv, poscnt, minbits,
                                     (float*)d_out, Bn);
}

// Round 10
// 145.431 us; speedup vs baseline: 4.0110x; 1.1189x over previous
//
#include <hip/hip_runtime.h>
#include <math.h>

#define EPS_N 1e-12f
#define MARGIN 0.3f
#define INF_BITS 0x7f800000u
#define NCLS 128     // label space (randint(0,128))
#define D 512
#define PADR 256     // padded rows after fh8 (safety margin)

typedef __attribute__((ext_vector_type(8))) short short8;   // (unused legacy)
typedef __attribute__((ext_vector_type(8))) char  char8;    // 8 i8 = 8 B
typedef __attribute__((ext_vector_type(4))) int   int4x;    // i8-MFMA A/B/acc (4 VGPR)
typedef __attribute__((ext_vector_type(4))) float float4v;

__device__ __forceinline__ void gl16(const void* g, void* l) {
    // 16B async global->LDS; global addr per-lane, LDS dest = uniform base + lane*16
    __builtin_amdgcn_global_load_lds((const __attribute__((address_space(1))) void*)g,
                                     (__attribute__((address_space(3))) void*)l, 16, 0, 0);
}

// ---------------------------------------------------------------------------
// K0: one-block bucketing, coalesced-metadata (unchanged).
// ---------------------------------------------------------------------------
__global__ __launch_bounds__(1024) void k_bucket(const int* __restrict__ lab, int Bn,
        int* __restrict__ pos, int* __restrict__ labp,
        int* __restrict__ cstart_g, int* __restrict__ ccnt_g,
        float* __restrict__ meanpos, float* __restrict__ pcinv,
        int* __restrict__ poscnt, unsigned* __restrict__ minbits) {
    __shared__ int cnt[NCLS], cs[NCLS + 1], off[NCLS], sa[NCLS], sb[NCLS];
    int tid = threadIdx.x;
    if (tid < NCLS) cnt[tid] = 0;
    __syncthreads();
    for (int i = tid; i < Bn; i += 1024) atomicAdd(&cnt[lab[i] & (NCLS - 1)], 1);
    __syncthreads();
    if (tid < NCLS) sa[tid] = cnt[tid];
    __syncthreads();
    int* src = sa; int* dst = sb;
    for (int ofs = 1; ofs < NCLS; ofs <<= 1) {          // Hillis-Steele inclusive
        if (tid < NCLS) dst[tid] = src[tid] + ((tid >= ofs) ? src[tid - ofs] : 0);
        __syncthreads();
        int* t = src; src = dst; dst = t;
    }
    if (tid < NCLS) {
        int ex = src[tid] - cnt[tid];                   // exclusive
        cs[tid] = ex;
        off[tid] = ex;
        cstart_g[tid] = ex;
        ccnt_g[tid] = cnt[tid];
    }
    if (tid == 0) cs[NCLS] = Bn;
    __syncthreads();
    // coalesced per-slot metadata: class(p) = largest l with cs[l] <= p
    for (int p = tid; p < Bn; p += 1024) {
        int lo = 0, hi = NCLS - 1;
        #pragma unroll
        for (int s = 0; s < 7; ++s) {
            int mid = (lo + hi + 1) >> 1;
            if (cs[mid] <= p) lo = mid; else hi = mid - 1;
        }
        int l = lo, m = cnt[l];
        labp[p] = l;
        poscnt[p] = m;
        pcinv[p] = 1.0f / (float)m;
        meanpos[p] = 0.f;
        minbits[p] = INF_BITS;
    }
    // pos scatter (reads coalesced; only pos[] store is scattered-by-class)
    for (int i = tid; i < Bn; i += 1024) {
        int l = lab[i] & (NCLS - 1);
        pos[i] = atomicAdd(&off[l], 1);
    }
}

// ---------------------------------------------------------------------------
// K1: normalize + per-row symmetric i8 quantization. One wave per row.
// q = rint(xn * 127/max|xn|); dequant scalar qs = max|xn|/127 stored f32.
// dot_true ~= (int)acc * qs_r * qs_c (int accumulate is exact).
// ---------------------------------------------------------------------------
__global__ __launch_bounds__(256) void k_normalize(const float* __restrict__ x,
        const int* __restrict__ pos, char* __restrict__ fh8,
        float* __restrict__ qs, float* __restrict__ sqp) {
    int w = threadIdx.x >> 6, L = threadIdx.x & 63;
    int row = blockIdx.x * 4 + w;
    const float* xr = x + (size_t)row * D + L * 8;
    float4 a = *(const float4*)xr;
    float4 b = *(const float4*)(xr + 4);
    float ss = a.x * a.x;
    ss = fmaf(a.y, a.y, ss); ss = fmaf(a.z, a.z, ss); ss = fmaf(a.w, a.w, ss);
    ss = fmaf(b.x, b.x, ss); ss = fmaf(b.y, b.y, ss);
    ss = fmaf(b.z, b.z, ss); ss = fmaf(b.w, b.w, ss);
    #pragma unroll
    for (int off = 32; off; off >>= 1) ss += __shfl_xor(ss, off, 64);
    float inv = 1.0f / fmaxf(sqrtf(ss), EPS_N);
    float e0 = a.x * inv, e1 = a.y * inv, e2 = a.z * inv, e3 = a.w * inv;
    float e4 = b.x * inv, e5 = b.y * inv, e6 = b.z * inv, e7 = b.w * inv;
    float mv = fmaxf(fmaxf(fmaxf(fabsf(e0), fabsf(e1)), fmaxf(fabsf(e2), fabsf(e3))),
                     fmaxf(fmaxf(fabsf(e4), fabsf(e5)), fmaxf(fabsf(e6), fabsf(e7))));
    #pragma unroll
    for (int off = 32; off; off >>= 1) mv = fmaxf(mv, __shfl_xor(mv, off, 64));
    float r127 = 127.0f / mv;
    int prow = pos[row];
    if (L == 0) {
        sqp[prow] = ss * inv * inv;      // ~1.0 (exact norm of fp32 normalize)
        qs[prow]  = mv * (1.0f / 127.0f);
    }
    char8 pk;
    pk[0] = (char)__float2int_rn(e0 * r127);
    pk[1] = (char)__float2int_rn(e1 * r127);
    pk[2] = (char)__float2int_rn(e2 * r127);
    pk[3] = (char)__float2int_rn(e3 * r127);
    pk[4] = (char)__float2int_rn(e4 * r127);
    pk[5] = (char)__float2int_rn(e5 * r127);
    pk[6] = (char)__float2int_rn(e6 * r127);
    pk[7] = (char)__float2int_rn(e7 * r127);
    *(char8*)(fh8 + (size_t)prow * D + L * 8) = pk;
}

// ---------------------------------------------------------------------------
// K2: per-class positive stats, i8 port of the R17 kernel. One block per
// class; stage class rows once per K-chunk (128 B/row, slot^(r&7) swizzle,
// both-sides), mfma_i32_16x16x64_i8, dequant by qs_r*qs_c in the epilogue,
// plain store (single writer).
// ---------------------------------------------------------------------------
__global__ __launch_bounds__(256) void k_posclass(
    const char* __restrict__ fh8, const float* __restrict__ sqp,
    const float* __restrict__ qs, const int* __restrict__ cstart_g,
    const int* __restrict__ ccnt_g, float* __restrict__ meanpos)
{
    const int c = blockIdx.x;
    const int s = cstart_g[c], n = ccnt_g[c];
    if (n <= 1) return;                         // no positives; meanpos stays 0

    __shared__ char SA[128 * 128];              // row chunk [r][K128] 16 KB
    __shared__ char SB[128 * 128];              // col chunk 16 KB
    __shared__ float sqr_sh[128], sqs[128], rs[128], qsr_sh[128], qss[128];

    const int tid = threadIdx.x, w = tid >> 6, L = tid & 63;
    const int lm = L & 15, ls = L >> 4;

    for (int rb = 0; rb < n; rb += 128) {
        const int nr = min(128, n - rb);
        __syncthreads();
        if (tid < 128) {
            rs[tid] = 0.f;
            sqr_sh[tid] = (tid < nr) ? sqp[s + rb + tid] : 0.f;
            qsr_sh[tid] = (tid < nr) ? qs[s + rb + tid] : 0.f;
        }
        for (int cb = 0; cb < n; cb += 128) {
            const int m = min(128, n - cb);
            const bool same = (rb == cb);
            __syncthreads();                    // prior epilogue done
            if (tid < 128) {
                sqs[tid] = (tid < m) ? sqp[s + cb + tid] : 0.f;
                qss[tid] = (tid < m) ? qs[s + cb + tid] : 0.f;
            }

            int4x acc[8][2];
            #pragma unroll
            for (int rt = 0; rt < 8; ++rt)
                #pragma unroll
                for (int ct = 0; ct < 2; ++ct) acc[rt][ct] = (int4x){0, 0, 0, 0};

            for (int k0 = 0; k0 < D; k0 += 128) {   // 4 chunks of 128 i8
                __syncthreads();                // prev MFMA reads done
                #pragma unroll
                for (int q = 0; q < 4; ++q) {   // 1024 16B slots (128 rows x 8)
                    int slot = tid + 256 * q;
                    int r = slot >> 3;
                    int u = (slot & 7) ^ (r & 7);   // pre-swizzled global seg
                    if (r < nr)
                        gl16(fh8 + (size_t)(s + rb + r) * D + k0 + u * 16,
                             &SA[(size_t)slot * 16]);
                }
                if (!same) {
                    #pragma unroll
                    for (int q = 0; q < 4; ++q) {
                        int slot = tid + 256 * q;
                        int r = slot >> 3;
                        int u = (slot & 7) ^ (r & 7);
                        if (r < m)
                            gl16(fh8 + (size_t)(s + cb + r) * D + k0 + u * 16,
                                 &SB[(size_t)slot * 16]);
                    }
                }
                __syncthreads();                // drains vmcnt: chunk landed
                const char* Bb = same ? SA : SB;
                #pragma unroll
                for (int h = 0; h < 2; ++h) {   // K=128 in 2 i8-MFMA sub-steps
                    int4x bf[2];
                    #pragma unroll
                    for (int ct = 0; ct < 2; ++ct) {
                        int cr = w * 32 + ct * 16 + lm;
                        bf[ct] = *(const int4x*)&Bb[cr * 128 + (((h * 4 + ls) ^ (cr & 7))) * 16];
                    }
                    #pragma unroll
                    for (int rt = 0; rt < 8; ++rt) {
                        int ar = rt * 16 + lm;
                        int4x af = *(const int4x*)&SA[ar * 128 + (((h * 4 + ls) ^ (ar & 7))) * 16];
                        #pragma unroll
                        for (int ct = 0; ct < 2; ++ct)
                            acc[rt][ct] = __builtin_amdgcn_mfma_i32_16x16x64_i8(af, bf[ct], acc[rt][ct], 0, 0, 0);
                    }
                }
            }
            // epilogue: masked dist row-sums. C/D: row = rt*16+ls*4+v, col = w*32+ct*16+lm
            #pragma unroll
            for (int rt = 0; rt < 8; ++rt) {
                #pragma unroll
                for (int v = 0; v < 4; ++v) {
                    int ri = rt * 16 + ls * 4 + v;
                    float sr = sqr_sh[ri];
                    float qr = qsr_sh[ri];
                    float sum = 0.f;
                    #pragma unroll
                    for (int ct = 0; ct < 2; ++ct) {
                        int ci = w * 32 + ct * 16 + lm;
                        float dot = (float)acc[rt][ct][v] * qr * qss[ci];
                        float d2 = sr + sqs[ci] - 2.0f * dot;
                        bool ok = (ri < nr) && (ci < m) && (rb + ri != cb + ci) && (d2 > 0.f);
                        sum += ok ? sqrtf(d2) : 0.f;
                    }
                    #pragma unroll
                    for (int off = 8; off; off >>= 1) sum += __shfl_xor(sum, off, 64);
                    if (lm == 0 && sum != 0.f) atomicAdd(&rs[ri], sum);
                }
            }
        }
        __syncthreads();
        if (tid < nr) meanpos[s + rb + tid] = rs[tid];   // single writer
    }
}

// ---------------------------------------------------------------------------
// K3: i8 port of the PROVEN R8 structure (same tiles, waves, swizzle, and
// 2-barrier loop — only the datatype changes). mfma_i32_16x16x64_i8 halves
// BOTH LDS traffic (128 B/row vs 256) and MFMA inst count (128 vs 256/wave)
// at identical 4-blocks/CU residency (acc 64 AGPR, frags 16B). 4 staging
// rounds of K=128 instead of 8 of K=64. Same slot^(r&7) both-sides swizzle
// on 128-B rows (exact R8 bank pattern, measured conflict-free).
// ---------------------------------------------------------------------------
__global__ __launch_bounds__(256, 4) void k_minsh_mfma(
    const char* __restrict__ fh8, const float* __restrict__ sqp,
    const float* __restrict__ qs, const int* __restrict__ labp,
    const float* __restrict__ meanpos, const float* __restrict__ pcinv,
    unsigned* __restrict__ minbits)
{
    int t = (blockIdx.x & 7) * 260 + (blockIdx.x >> 3);   // XCD-bijective
    int rq = (int)((sqrtf(8.0f * (float)t + 1.0f) - 1.0f) * 0.5f);
    while ((rq + 1) * (rq + 2) / 2 <= t) ++rq;
    while (rq * (rq + 1) / 2 > t) --rq;
    int cq = t - rq * (rq + 1) / 2;
    const int i0 = cq * 128, j0 = rq * 128;
    const bool diag = (i0 == j0);

    __shared__ char LA[2][128 * 128];             // 32 KB (two 16-KB tiles)
    __shared__ float s_mp2r[128], s_mp2c[128], s_sqr[128], s_sqc[128];
    __shared__ float s_qsr[128], s_qsc[128];
    __shared__ int s_labr[128], s_labc[128];

    const int tid = threadIdx.x;
    const int w = tid >> 6, L = tid & 63;

    if (tid < 128) {
        float mp = meanpos[i0 + tid] * pcinv[i0 + tid];
        s_mp2r[tid] = mp * mp;
        s_sqr[tid]  = sqp[i0 + tid];
        s_qsr[tid]  = qs[i0 + tid];
        s_labr[tid] = labp[i0 + tid];
    } else {
        int q = tid - 128;
        float mp = meanpos[j0 + q] * pcinv[j0 + q];
        s_mp2c[q] = mp * mp;
        s_sqc[q]  = sqp[j0 + q];
        s_qsc[q]  = qs[j0 + q];
        s_labc[q] = labp[j0 + q];
    }

    const char* msrc = fh8 + (size_t)((w < 2) ? i0 : j0) * D;
    char* mylds = &LA[(w < 2) ? 0 : 1][(w & 1) * 64 * 128];
    const int srow = L >> 3;
    const int sseg = L & 7;

    int4x acc[4][4];
    #pragma unroll
    for (int a = 0; a < 4; ++a)
        #pragma unroll
        for (int bq = 0; bq < 4; ++bq) acc[a][bq] = (int4x){0, 0, 0, 0};

    const int rw = (w >> 1) * 64, cw = (w & 1) * 64;
    const int lm = L & 15, ls = L >> 4;

    for (int k0 = 0; k0 < D; k0 += 128) {         // 4 staging rounds (K=128)
        __syncthreads();
        #pragma unroll
        for (int it = 0; it < 8; ++it) {          // 8 rows x 128 B per it
            int rmat = (w & 1) * 64 + it * 8 + srow;
            int seg = sseg ^ (rmat & 7);
            gl16(msrc + (size_t)rmat * D + k0 + seg * 16, mylds + it * 1024);
        }
        __syncthreads();
        #pragma unroll
        for (int h = 0; h < 2; ++h) {             // 2 x K=64 MFMA sub-steps
            int4x ah[4], bh[4];
            #pragma unroll
            for (int mi = 0; mi < 4; ++mi) {
                int r = rw + mi * 16 + lm;
                int slot = r * 8 + ((h * 4 + ls) ^ (r & 7));
                ah[mi] = *(const int4x*)&LA[0][slot * 16];
            }
            #pragma unroll
            for (int ni = 0; ni < 4; ++ni) {
                int cc = cw + ni * 16 + lm;
                int slot = cc * 8 + ((h * 4 + ls) ^ (cc & 7));
                bh[ni] = *(const int4x*)&LA[1][slot * 16];
            }
            #pragma unroll
            for (int ni = 0; ni < 4; ++ni)
                #pragma unroll
                for (int mi = 0; mi < 4; ++mi)
                    acc[mi][ni] = __builtin_amdgcn_mfma_i32_16x16x64_i8(ah[mi], bh[ni], acc[mi][ni], 0, 0, 0);
        }
    }

    // d2-space epilogue. C/D: row = rw+mi*16+ls*4+v, col = cw+ni*16+lm
    const float INFF = __uint_as_float(INF_BITS);
    float sc[4], mp2c[4], qc[4];
    int lc[4];
    #pragma unroll
    for (int ni = 0; ni < 4; ++ni) {
        int cl = cw + ni * 16 + lm;
        sc[ni]   = s_sqc[cl];
        mp2c[ni] = s_mp2c[cl];
        qc[ni]   = s_qsc[cl];
        lc[ni]   = s_labc[cl];
    }
    float vminc[4];
    #pragma unroll
    for (int ni = 0; ni < 4; ++ni) vminc[ni] = INFF;

    #pragma unroll
    for (int mi = 0; mi < 4; ++mi) {
        #pragma unroll
        for (int v = 0; v < 4; ++v) {
            int rl = rw + mi * 16 + ls * 4 + v;
            float mp2r = s_mp2r[rl];
            float sr   = s_sqr[rl];
            float qr   = s_qsr[rl];
            int   li   = s_labr[rl];
            float vminr = INFF;
            #pragma unroll
            for (int ni = 0; ni < 4; ++ni) {
                float dot = (float)acc[mi][ni][v] * qr * qc[ni];
                float d2 = fmaf(-2.0f, dot, sr + sc[ni]);
                bool neq = (li != lc[ni]);
                vminr     = fminf(vminr,     (neq && d2 > mp2r)     ? d2 : INFF);
                vminc[ni] = fminf(vminc[ni], (neq && d2 > mp2c[ni]) ? d2 : INFF);
            }
            #pragma unroll
            for (int off = 8; off; off >>= 1)
                vminr = fminf(vminr, __shfl_xor(vminr, off, 64));
            if (lm == 0 && __float_as_uint(vminr) != INF_BITS)
                atomicMin(&minbits[i0 + rl], __float_as_uint(vminr));
        }
    }
    if (!diag) {
        #pragma unroll
        for (int ni = 0; ni < 4; ++ni) {
            float vc = vminc[ni];
            vc = fminf(vc, __shfl_xor(vc, 16, 64));
            vc = fminf(vc, __shfl_xor(vc, 32, 64));
            if (ls == 0 && __float_as_uint(vc) != INF_BITS)
                atomicMin(&minbits[j0 + cw + ni * 16 + lm], __float_as_uint(vc));
        }
    }
}

// ---------------------------------------------------------------------------
// K4: final reduction (unchanged).
// ---------------------------------------------------------------------------
__global__ __launch_bounds__(1024) void k_finish(const float* __restrict__ meanpos,
        const float* __restrict__ pcinv, const int* __restrict__ poscnt,
        const unsigned* __restrict__ minbits, float* __restrict__ out, int Bn) {
    float lsum = 0.f; int lcnt = 0;
    for (int i = threadIdx.x; i < Bn; i += 1024) {
        int pc = poscnt[i];
        bool valid = (pc > 1) && (pc < Bn);
        unsigned mb = minbits[i];
        if (valid && mb != INF_BITS) {
            float v = fmaf(meanpos[i], pcinv[i], MARGIN - sqrtf(__uint_as_float(mb)));
            lsum += (v > 0.f) ? v : 0.f;
            lcnt += 1;
        }
    }
    __shared__ float ssum[16]; __shared__ int scnt[16];
    int lane = threadIdx.x & 63, wid = threadIdx.x >> 6;
    #pragma unroll
    for (int off = 32; off; off >>= 1) {
        lsum += __shfl_down(lsum, off, 64);
        lcnt += __shfl_down(lcnt, off, 64);
    }
    if (lane == 0) { ssum[wid] = lsum; scnt[wid] = lcnt; }
    __syncthreads();
    if (threadIdx.x == 0) {
        float s = 0.f; int c = 0;
        #pragma unroll
        for (int q = 0; q < 16; ++q) { s += ssum[q]; c += scnt[q]; }
        out[0] = (c > 0) ? s / (float)c : 0.f;
    }
}

// ---------------------------------------------------------------------------
extern "C" void kernel_launch(void* const* d_in, const int* in_sizes, int n_in,
                              void* d_out, int out_size, void* d_ws, size_t ws_size,
                              hipStream_t stream) {
    const float* x = (const float*)d_in[0];
    const int* lab = (const int*)d_in[1];
    int Bn = in_sizes[1];                 // 8192; D fixed at 512

    size_t nd8 = (size_t)(Bn + PADR) * D; // i8 feature matrix (bytes)
    char* fh8         = (char*)d_ws;
    float* sqp        = (float*)(fh8 + nd8);
    float* qsv        = sqp + Bn;         // per-row dequant scalars
    float* meanpos    = qsv + Bn;         // raw dist-sums
    float* pcinv      = meanpos + Bn;
    int* poscnt       = (int*)(pcinv + Bn);
    unsigned* minbits = (unsigned*)(poscnt + Bn);
    int* pos          = (int*)(minbits + Bn);
    int* labp         = pos + Bn;
    int* cstart_g     = labp + Bn;
    int* ccnt_g       = cstart_g + NCLS;

    k_bucket<<<1, 1024, 0, stream>>>(lab, Bn, pos, labp, cstart_g, ccnt_g,
                                     meanpos, pcinv, poscnt, minbits);
    k_normalize<<<Bn / 4, 256, 0, stream>>>(x, pos, fh8, qsv, sqp);
    k_posclass<<<NCLS, 256, 0, stream>>>(fh8, sqp, qsv, cstart_g, ccnt_g, meanpos);
    int nb = Bn / 128;
    int T = nb * (nb + 1) / 2;            // 2080 = 8*260 (XCD-bijective)
    k_minsh_mfma<<<T, 256, 0, stream>>>(fh8, sqp, qsv, labp, meanpos, pcinv, minbits);
    k_finish<<<1, 1024, 0, stream>>>(meanpos, pcinv, poscnt, minbits,
                                     (float*)d_out, Bn);
}